// Round 1
// baseline (50991.956 us; speedup 1.0000x reference)
//
#include <hip/hip_runtime.h>

// 2-layer LSTM, S=512, B=32, H=1024, E=512.
// Baseline strategy: one kernel launch per (timestep, layer) = 1024 launches,
// all state (h, c per step) lives directly in d_out's hiddens/cells regions,
// so NO workspace is needed and stream ordering provides the recurrence dep.
// fp32 compute throughout (matches reference numerics).

#define S_LEN 512
#define BATCH 32
#define HID   1024
#define EMB   512
#define KC    256   // K-chunk staged in LDS per iteration

__device__ __forceinline__ float sigmoidf_(float x) {
    return 1.0f / (1.0f + expf(-x));
}

// One LSTM cell step for one layer.
//   gates[b][r] = sum_k A[b][k] * Wrow_r[k] + bi[r] + bh[r]
//   A = concat(x_input (B x K1), Hprev (B x HID)) along k.
// x_input row b = xidx ? xsrc + xidx[b]*K1 (embedding gather) : xsrc + b*K1.
// Gate order (jnp.split): i=[0,H) f=[H,2H) g=[2H,3H) o=[3H,4H).
//
// Block: 256 threads = 32 batch x 2 j-columns x 4 K-splits.
//   t = b + 32*jl + 64*ks. Grid 512 blocks -> j = blockIdx*2 + jl covers 0..1023.
// Per chunk of KC=256 virtual-k, all threads cooperatively stage A into LDS,
// then each thread accumulates its 64-wide k sub-range for its 4 gate rows.
// Weight reads: lanes 0..31 of each half-wave share one address -> broadcast.
__global__ __launch_bounds__(256)
void lstm_step(const float* __restrict__ Wi, const float* __restrict__ Wh,
               const float* __restrict__ bi, const float* __restrict__ bh,
               const float* __restrict__ xsrc, const int* __restrict__ xidx, int K1,
               const float* __restrict__ Hprev, const float* __restrict__ Cprev,
               float* __restrict__ Hout, float* __restrict__ Cout,
               float* __restrict__ Hout2)
{
    __shared__ float As[32][KC + 4];   // +4 floats pad: breaks 32-way bank conflict
    __shared__ float red[256][5];      // +1 pad

    const int t  = threadIdx.x;
    const int b  = t & 31;
    const int jl = (t >> 5) & 1;
    const int ks = t >> 6;                       // 0..3
    const int j  = (blockIdx.x << 1) + jl;       // 0..1023

    const int Ktot = K1 + HID;
    const int NC   = Ktot / KC;                  // 6 (layer0) or 8 (layer1)

    float acc0 = 0.f, acc1 = 0.f, acc2 = 0.f, acc3 = 0.f;

    for (int c = 0; c < NC; ++c) {
        const int  k0  = c * KC;
        const bool isX = (k0 < K1);              // chunk boundaries align with K1

        // ---- stage A chunk (32 rows x KC floats) into LDS, coalesced ----
        #pragma unroll
        for (int i = 0; i < 8; ++i) {
            const int idx4 = t + (i << 8);       // 0..2047 float4 slots
            const int row  = idx4 >> 6;          // 0..31
            const int c4   = idx4 & 63;          // 0..63
            const float* src;
            if (isX) {
                const size_t r0 = xidx ? (size_t)xidx[row] : (size_t)row;
                src = xsrc + r0 * (size_t)K1 + k0;
            } else {
                src = Hprev + (size_t)row * HID + (k0 - K1);
            }
            const float4 v = *(const float4*)(src + (c4 << 2));
            *(float4*)&As[row][c4 << 2] = v;
        }
        __syncthreads();

        // ---- accumulate this thread's 64-wide sub-range of the chunk ----
        const float* W      = isX ? Wi : Wh;
        const int    stride = isX ? K1 : HID;
        const int    kw     = k0 + (ks << 6) - (isX ? 0 : K1);
        const float* w0 = W + (size_t)(j         ) * stride + kw;
        const float* w1 = W + (size_t)(j + 1024  ) * stride + kw;
        const float* w2 = W + (size_t)(j + 2048  ) * stride + kw;
        const float* w3 = W + (size_t)(j + 3072  ) * stride + kw;
        const float* a  = &As[b][ks << 6];

        #pragma unroll 4
        for (int kk = 0; kk < 64; kk += 4) {
            const float4 av = *(const float4*)(a + kk);
            float4 w;
            w = *(const float4*)(w0 + kk);
            acc0 = fmaf(av.x, w.x, acc0); acc0 = fmaf(av.y, w.y, acc0);
            acc0 = fmaf(av.z, w.z, acc0); acc0 = fmaf(av.w, w.w, acc0);
            w = *(const float4*)(w1 + kk);
            acc1 = fmaf(av.x, w.x, acc1); acc1 = fmaf(av.y, w.y, acc1);
            acc1 = fmaf(av.z, w.z, acc1); acc1 = fmaf(av.w, w.w, acc1);
            w = *(const float4*)(w2 + kk);
            acc2 = fmaf(av.x, w.x, acc2); acc2 = fmaf(av.y, w.y, acc2);
            acc2 = fmaf(av.z, w.z, acc2); acc2 = fmaf(av.w, w.w, acc2);
            w = *(const float4*)(w3 + kk);
            acc3 = fmaf(av.x, w.x, acc3); acc3 = fmaf(av.y, w.y, acc3);
            acc3 = fmaf(av.z, w.z, acc3); acc3 = fmaf(av.w, w.w, acc3);
        }
        __syncthreads();
    }

    // ---- reduce the 4 K-splits, then pointwise LSTM ----
    red[t][0] = acc0; red[t][1] = acc1; red[t][2] = acc2; red[t][3] = acc3;
    __syncthreads();

    if (t < 64) {   // ks==0 threads: one per (b, j) pair of this block
        float tot[4];
        #pragma unroll
        for (int g = 0; g < 4; ++g) {
            const int r = j + (g << 10);
            tot[g] = red[t][g] + red[t + 64][g] + red[t + 128][g] + red[t + 192][g]
                   + bi[r] + bh[r];
        }
        const float ig = sigmoidf_(tot[0]);
        const float fg = sigmoidf_(tot[1]);
        const float gg = tanhf(tot[2]);
        const float og = sigmoidf_(tot[3]);
        const size_t o  = (size_t)b * HID + j;
        const float  cp = Cprev[o];
        const float  cn = fg * cp + ig * gg;
        const float  hn = og * tanhf(cn);
        Cout[o] = cn;
        Hout[o] = hn;
        if (Hout2) Hout2[o] = hn;
    }
}

extern "C" void kernel_launch(void* const* d_in, const int* in_sizes, int n_in,
                              void* d_out, int out_size, void* d_ws, size_t ws_size,
                              hipStream_t stream)
{
    (void)in_sizes; (void)n_in; (void)out_size; (void)d_ws; (void)ws_size;

    const int*   x     = (const int*)  d_in[0];   // (S, B) int32
    const float* embed = (const float*)d_in[1];   // (V, E)
    const float* Wi0   = (const float*)d_in[2];   // (4H, E)
    const float* Wh0   = (const float*)d_in[3];   // (4H, H)
    const float* bi0   = (const float*)d_in[4];
    const float* bh0   = (const float*)d_in[5];
    const float* Wi1   = (const float*)d_in[6];   // (4H, H)
    const float* Wh1   = (const float*)d_in[7];   // (4H, H)
    const float* bi1   = (const float*)d_in[8];
    const float* bh1   = (const float*)d_in[9];
    const float* h0in  = (const float*)d_in[10];  // (L, B, H)
    const float* c0in  = (const float*)d_in[11];  // (L, B, H)

    float* out     = (float*)d_out;
    const size_t BH = (size_t)BATCH * HID;              // 32768
    float* outputs = out;                               // (S,1,B,H)
    float* hiddens = out + (size_t)S_LEN * BH;          // (S,L,B,H)
    float* cells   = out + 3 * (size_t)S_LEN * BH;      // (S,L,B,H)

    for (int s = 0; s < S_LEN; ++s) {
        // ---- layer 0: input = embed[x[s]], state from step s-1 ----
        const float* Hp0 = s ? hiddens + ((size_t)(s - 1) * 2 + 0) * BH : h0in;
        const float* Cp0 = s ? cells   + ((size_t)(s - 1) * 2 + 0) * BH : c0in;
        float* H0o = hiddens + ((size_t)s * 2 + 0) * BH;
        float* C0o = cells   + ((size_t)s * 2 + 0) * BH;
        lstm_step<<<512, 256, 0, stream>>>(Wi0, Wh0, bi0, bh0,
                                           embed, x + (size_t)s * BATCH, EMB,
                                           Hp0, Cp0, H0o, C0o, nullptr);

        // ---- layer 1: input = h0[s] (just written), state from step s-1 ----
        const float* Hp1 = s ? hiddens + ((size_t)(s - 1) * 2 + 1) * BH : h0in + BH;
        const float* Cp1 = s ? cells   + ((size_t)(s - 1) * 2 + 1) * BH : c0in + BH;
        float* H1o = hiddens + ((size_t)s * 2 + 1) * BH;
        float* C1o = cells   + ((size_t)s * 2 + 1) * BH;
        lstm_step<<<512, 256, 0, stream>>>(Wi1, Wh1, bi1, bh1,
                                           H0o, nullptr, HID,
                                           Hp1, Cp1, H1o, C1o, outputs + (size_t)s * BH);
    }
}